// Round 6
// baseline (440.071 us; speedup 1.0000x reference)
//
#include <hip/hip_runtime.h>
#include <hip/hip_fp16.h>
#include <math.h>

namespace {
constexpr int NCOL = 384, NROW = 64, NVIEW = 16, NSAMP = 256;
constexpr float DET_U = 1.2f, DET_V = 1.2f;
constexpr float ISO = 500.0f, SDD = 1000.0f;
constexpr double SQRT3 = 1.7320508075688772;
constexpr float DT = (float)SQRT3;                          // RAY_LEN / NSAMP
constexpr float T0 = (float)(500.0 - SQRT3 * 256.0 * 0.5); // ISO - RAY_LEN/2
constexpr size_t VOL_N = 256u * 256u * 256u;               // 16.7M voxels
}

// ---------- shared helpers ---------------------------------------------------

// t-interval where p0 + t*d lies in [LO, HI]; empty -> [1e30, -1e30]
__device__ __forceinline__ void axis_interval(float p0, float d, float LO, float HI,
                                              float& tlo, float& thi) {
    if (fabsf(d) < 1e-7f) {
        if (p0 < LO || p0 > HI) { tlo = 1e30f; thi = -1e30f; }
        else                    { tlo = -1e30f; thi = 1e30f; }
    } else {
        const float r = 1.0f / d;
        const float t1 = (LO - p0) * r, t2 = (HI - p0) * r;
        tlo = fminf(t1, t2); thi = fmaxf(t1, t2);
    }
}

// general (shell) sample on the ORIGINAL fp32 volume: per-corner check
__device__ __forceinline__ float sample_shell(const float* __restrict__ vol,
                                              float vx, float vy, float vz) {
    if (!(vx > -1.0f && vx < 256.0f && vy > -1.0f && vy < 256.0f &&
          vz > -1.0f && vz < 256.0f))
        return 0.0f;
    const float fx0 = floorf(vx), fy0 = floorf(vy), fz0 = floorf(vz);
    const int x0 = (int)fx0, y0 = (int)fy0, z0 = (int)fz0;
    const float fx = vx - fx0, fy = vy - fy0, fz = vz - fz0;
    float sum = 0.0f;
    #pragma unroll
    for (int dzz = 0; dzz < 2; ++dzz) {
        const float wz = dzz ? fz : 1.0f - fz;
        const int zi = z0 + dzz;
        #pragma unroll
        for (int dyy = 0; dyy < 2; ++dyy) {
            const float wy = dyy ? fy : 1.0f - fy;
            const int yi = y0 + dyy;
            #pragma unroll
            for (int dxx = 0; dxx < 2; ++dxx) {
                const float wx = dxx ? fx : 1.0f - fx;
                const int xi = x0 + dxx;
                if ((unsigned)xi < 256u && (unsigned)yi < 256u && (unsigned)zi < 256u)
                    sum += wz * wy * wx * vol[(zi << 16) | (yi << 8) | xi];
            }
        }
    }
    return sum;
}

struct Spans { int g0, s0, s1, g1; float dx, dy, dz, bx, by, bz; };

__device__ __forceinline__ Spans ray_setup(const float* __restrict__ angles, int tid) {
    Spans sp;
    const int col = tid % NCOL;
    const int rv  = tid / NCOL;
    const int row = rv % NROW;
    const int view = rv / NROW;

    const float beta = angles[view];
    const float cb = cosf(beta), sb = sinf(beta);
    const float u = (col - NCOL * 0.5f + 0.5f) * DET_U;
    const float v = (row - NROW * 0.5f + 0.5f) * DET_V;

    const float sx = ISO * cb, sy = ISO * sb;               // source (z=0)
    const float detx = -(SDD - ISO) * cb - u * sb;
    const float dety = -(SDD - ISO) * sb + u * cb;
    const float detz = v;

    float dx = detx - sx, dy = dety - sy, dz = detz;
    const float inv = 1.0f / sqrtf(dx * dx + dy * dy + dz * dz);
    dx *= inv; dy *= inv; dz *= inv;
    sp.dx = dx; sp.dy = dy; sp.dz = dz;
    sp.bx = sx + 127.5f; sp.by = sy + 127.5f; sp.bz = 127.5f;

    float xl, xh, yl, yh, zl, zh;
    axis_interval(sp.bx, dx, 0.01f, 254.99f, xl, xh);
    axis_interval(sp.by, dy, 0.01f, 254.99f, yl, yh);
    axis_interval(sp.bz, dz, 0.01f, 254.99f, zl, zh);
    const float tin  = fmaxf(xl, fmaxf(yl, zl));
    const float tout = fminf(xh, fminf(yh, zh));

    axis_interval(sp.bx, dx, -1.05f, 256.05f, xl, xh);
    axis_interval(sp.by, dy, -1.05f, 256.05f, yl, yh);
    axis_interval(sp.bz, dz, -1.05f, 256.05f, zl, zh);
    const float glo = fmaxf(xl, fmaxf(yl, zl));
    const float ghi = fminf(xh, fminf(yh, zh));

    const float invdt = 1.0f / DT;
    float g0f = floorf((glo - T0) * invdt - 0.5f);
    float g1f = ceilf((ghi - T0) * invdt - 0.5f) + 1.0f;
    float s0f = ceilf((tin - T0) * invdt - 0.5f + 0.01f);
    float s1f = floorf((tout - T0) * invdt - 0.5f - 0.01f) + 1.0f;
    int g0 = (int)fminf(fmaxf(g0f, 0.0f), 256.0f);
    int g1 = (int)fminf(fmaxf(g1f, 0.0f), 256.0f);
    int s0 = (int)fminf(fmaxf(s0f, 0.0f), 256.0f);
    int s1 = (int)fminf(fmaxf(s1f, 0.0f), 256.0f);
    s0 = max(s0, g0); s1 = min(s1, g1);
    if (s1 < s0) { s0 = g0; s1 = g0; }
    sp.g0 = g0; sp.s0 = s0; sp.s1 = s1; sp.g1 = g1;
    return sp;
}

// trilinear from 4 packed x-pairs (lo = x0, hi = x0+1)
__device__ __forceinline__ float trilerp_h2(__half2 vy0z0, __half2 vy1z0,
                                            __half2 vy0z1, __half2 vy1z1,
                                            float fx, float fy, float fz) {
    const float c00 = fmaf(fx, __half2float(__high2half(vy0z0)) - __half2float(__low2half(vy0z0)), __half2float(__low2half(vy0z0)));
    const float c01 = fmaf(fx, __half2float(__high2half(vy1z0)) - __half2float(__low2half(vy1z0)), __half2float(__low2half(vy1z0)));
    const float c10 = fmaf(fx, __half2float(__high2half(vy0z1)) - __half2float(__low2half(vy0z1)), __half2float(__low2half(vy0z1)));
    const float c11 = fmaf(fx, __half2float(__high2half(vy1z1)) - __half2float(__low2half(vy1z1)), __half2float(__low2half(vy1z1)));
    const float c0 = fmaf(fy, c01 - c00, c00);
    const float c1 = fmaf(fy, c11 - c10, c10);
    return fmaf(fz, c1 - c0, c0);
}

// ---------- pre-pass: pack fp32 volume into half2 x-pairs --------------------
__global__ __launch_bounds__(256) void pack_kernel(const float* __restrict__ vol,
                                                   __half2* __restrict__ out) {
    const unsigned i = blockIdx.x * 256u + threadIdx.x;   // 16.7M
    const unsigned x = i & 255u;
    const float a = vol[i];
    const float b = (x < 255u) ? vol[i + 1] : a;
    out[i] = __floats2half2_rn(a, b);
}

// ---------- main kernel: half2-pair gathers, 2-sample interleave -------------
__global__ __launch_bounds__(128) void projector3d_h2_kernel(
    const float* __restrict__ vol,       // fp32 original (shell path)
    const __half2* __restrict__ vol16,   // packed x-pairs
    const float* __restrict__ angles,
    float* __restrict__ out)
{
    // XCD swizzle: 3072 blocks, 3072 % 8 == 0 -> bijective
    const int nwg = (NVIEW * NROW * NCOL) / 128;   // 3072
    const int cpx = nwg / 8;                       // 384
    const int bid = blockIdx.x;
    const int swz = (bid % 8) * cpx + bid / 8;
    const int tid = swz * 128 + threadIdx.x;

    const Spans sp = ray_setup(angles, tid);
    const float dx = sp.dx, dy = sp.dy, dz = sp.dz;
    const float bx = sp.bx, by = sp.by, bz = sp.bz;

    float acc = 0.0f;

    for (int s = sp.g0; s < sp.s0; ++s) {
        const float t = T0 + (s + 0.5f) * DT;
        acc += sample_shell(vol, fmaf(t, dx, bx), fmaf(t, dy, by), fmaf(t, dz, bz));
    }

    float accA = 0.0f, accB = 0.0f;
    int s = sp.s0;
    for (; s + 1 < sp.s1; s += 2) {
        const float tA = T0 + (s + 0.5f) * DT;
        const float tB = tA + DT;
        // sample A coords
        const float axf = fmaf(tA, dx, bx), ayf = fmaf(tA, dy, by), azf = fmaf(tA, dz, bz);
        const float bxf = fmaf(tB, dx, bx), byf = fmaf(tB, dy, by), bzf = fmaf(tB, dz, bz);
        const float ax0 = floorf(axf), ay0 = floorf(ayf), az0 = floorf(azf);
        const float bx0 = floorf(bxf), by0 = floorf(byf), bz0 = floorf(bzf);
        const int aix = (int)ax0, aiy = (int)ay0, aiz = (int)az0;
        const int bix = (int)bx0, biy = (int)by0, biz = (int)bz0;

        const __half2* pA = vol16 + ((aiz << 16) | (aiy << 8) | aix);
        const __half2* pB = vol16 + ((biz << 16) | (biy << 8) | bix);
        // issue all 8 loads before any dependent math
        const __half2 A00 = pA[0],     A01 = pA[256];
        const __half2 A10 = pA[65536], A11 = pA[65792];
        const __half2 B00 = pB[0],     B01 = pB[256];
        const __half2 B10 = pB[65536], B11 = pB[65792];

        accA += trilerp_h2(A00, A01, A10, A11, axf - ax0, ayf - ay0, azf - az0);
        accB += trilerp_h2(B00, B01, B10, B11, bxf - bx0, byf - by0, bzf - bz0);
    }
    if (s < sp.s1) {
        const float t = T0 + (s + 0.5f) * DT;
        const float vx = fmaf(t, dx, bx), vy = fmaf(t, dy, by), vz = fmaf(t, dz, bz);
        const float x0 = floorf(vx), y0 = floorf(vy), z0 = floorf(vz);
        const __half2* p = vol16 + (((int)z0 << 16) | ((int)y0 << 8) | (int)x0);
        accA += trilerp_h2(p[0], p[256], p[65536], p[65792],
                           vx - x0, vy - y0, vz - z0);
    }
    acc += accA + accB;

    for (int s2 = sp.s1; s2 < sp.g1; ++s2) {
        const float t = T0 + (s2 + 0.5f) * DT;
        acc += sample_shell(vol, fmaf(t, dx, bx), fmaf(t, dy, by), fmaf(t, dz, bz));
    }

    out[tid] = acc * DT;
}

// ---------- fallback (fp32, round-5 kernel) for small ws ---------------------
__global__ __launch_bounds__(256) void projector3d_f32_kernel(
    const float* __restrict__ vol,
    const float* __restrict__ angles,
    float* __restrict__ out)
{
    const int nwg = (NVIEW * NROW * NCOL) / 256;
    const int cpx = nwg / 8;
    const int bid = blockIdx.x;
    const int swz = (bid % 8) * cpx + bid / 8;
    const int tid = swz * 256 + threadIdx.x;

    const Spans sp = ray_setup(angles, tid);
    const float dx = sp.dx, dy = sp.dy, dz = sp.dz;
    const float bx = sp.bx, by = sp.by, bz = sp.bz;

    float acc = 0.0f;
    for (int s = sp.g0; s < sp.s0; ++s) {
        const float t = T0 + (s + 0.5f) * DT;
        acc += sample_shell(vol, fmaf(t, dx, bx), fmaf(t, dy, by), fmaf(t, dz, bz));
    }
    #pragma unroll 4
    for (int s = sp.s0; s < sp.s1; ++s) {
        const float t = T0 + (s + 0.5f) * DT;
        const float vx = fmaf(t, dx, bx), vy = fmaf(t, dy, by), vz = fmaf(t, dz, bz);
        const float fx0 = floorf(vx), fy0 = floorf(vy), fz0 = floorf(vz);
        const int x0 = (int)fx0, y0 = (int)fy0, z0 = (int)fz0;
        const float fx = vx - fx0, fy = vy - fy0, fz = vz - fz0;
        const float* p = vol + ((z0 << 16) | (y0 << 8) | x0);
        const float v000 = p[0],     v001 = p[1];
        const float v010 = p[256],   v011 = p[257];
        const float v100 = p[65536], v101 = p[65537];
        const float v110 = p[65792], v111 = p[65793];
        const float c00 = fmaf(fx, v001 - v000, v000);
        const float c01 = fmaf(fx, v011 - v010, v010);
        const float c10 = fmaf(fx, v101 - v100, v100);
        const float c11 = fmaf(fx, v111 - v110, v110);
        const float c0 = fmaf(fy, c01 - c00, c00);
        const float c1 = fmaf(fy, c11 - c10, c10);
        acc += fmaf(fz, c1 - c0, c0);
    }
    for (int s = sp.s1; s < sp.g1; ++s) {
        const float t = T0 + (s + 0.5f) * DT;
        acc += sample_shell(vol, fmaf(t, dx, bx), fmaf(t, dy, by), fmaf(t, dz, bz));
    }
    out[tid] = acc * DT;
}

extern "C" void kernel_launch(void* const* d_in, const int* in_sizes, int n_in,
                              void* d_out, int out_size, void* d_ws, size_t ws_size,
                              hipStream_t stream) {
    const float* vol    = (const float*)d_in[0];
    const float* angles = (const float*)d_in[1];
    float* out = (float*)d_out;

    const size_t need = VOL_N * sizeof(__half2) / 2;  // 16.7M half2 = 67.1 MB
    if (ws_size >= VOL_N * 4u) {
        __half2* vol16 = (__half2*)d_ws;
        pack_kernel<<<(int)(VOL_N / 256), 256, 0, stream>>>(vol, vol16);
        const int grid = (NVIEW * NROW * NCOL) / 128;   // 3072
        projector3d_h2_kernel<<<grid, 128, 0, stream>>>(vol, vol16, angles, out);
    } else {
        (void)need;
        const int grid = (NVIEW * NROW * NCOL) / 256;   // 1536
        projector3d_f32_kernel<<<grid, 256, 0, stream>>>(vol, angles, out);
    }
}

// Round 8
// 350.428 us; speedup vs baseline: 1.2558x; 1.2558x over previous
//
#include <hip/hip_runtime.h>
#include <math.h>

namespace {
constexpr int NCOL = 384, NROW = 64, NVIEW = 16, NSAMP = 256;
constexpr float DET_U = 1.2f, DET_V = 1.2f;
constexpr float ISO = 500.0f, SDD = 1000.0f;
constexpr double SQRT3 = 1.7320508075688772;
constexpr float DT = (float)SQRT3;                          // RAY_LEN / NSAMP
constexpr float T0 = (float)(500.0 - SQRT3 * 256.0 * 0.5); // ISO - RAY_LEN/2
constexpr size_t VOL_N = 256u * 256u * 256u;               // 16.7M voxels
}

// t-interval where p0 + t*d lies in [LO, HI]; empty -> [1e30, -1e30]
__device__ __forceinline__ void axis_interval(float p0, float d, float LO, float HI,
                                              float& tlo, float& thi) {
    if (fabsf(d) < 1e-7f) {
        if (p0 < LO || p0 > HI) { tlo = 1e30f; thi = -1e30f; }
        else                    { tlo = -1e30f; thi = 1e30f; }
    } else {
        const float r = 1.0f / d;
        const float t1 = (LO - p0) * r, t2 = (HI - p0) * r;
        tlo = fminf(t1, t2); thi = fmaxf(t1, t2);
    }
}

// general (shell) sample on the ORIGINAL fp32 volume: per-corner check
__device__ __forceinline__ float sample_shell(const float* __restrict__ vol,
                                              float vx, float vy, float vz) {
    if (!(vx > -1.0f && vx < 256.0f && vy > -1.0f && vy < 256.0f &&
          vz > -1.0f && vz < 256.0f))
        return 0.0f;
    const float fx0 = floorf(vx), fy0 = floorf(vy), fz0 = floorf(vz);
    const int x0 = (int)fx0, y0 = (int)fy0, z0 = (int)fz0;
    const float fx = vx - fx0, fy = vy - fy0, fz = vz - fz0;
    float sum = 0.0f;
    #pragma unroll
    for (int dzz = 0; dzz < 2; ++dzz) {
        const float wz = dzz ? fz : 1.0f - fz;
        const int zi = z0 + dzz;
        #pragma unroll
        for (int dyy = 0; dyy < 2; ++dyy) {
            const float wy = dyy ? fy : 1.0f - fy;
            const int yi = y0 + dyy;
            #pragma unroll
            for (int dxx = 0; dxx < 2; ++dxx) {
                const float wx = dxx ? fx : 1.0f - fx;
                const int xi = x0 + dxx;
                if ((unsigned)xi < 256u && (unsigned)yi < 256u && (unsigned)zi < 256u)
                    sum += wz * wy * wx * vol[(zi << 16) | (yi << 8) | xi];
            }
        }
    }
    return sum;
}

struct Spans { int g0, s0, s1, g1; float dx, dy, dz, bx, by, bz; float cb, sb; };

__device__ __forceinline__ Spans ray_setup(const float* __restrict__ angles, int tid) {
    Spans sp;
    const int col = tid % NCOL;
    const int rv  = tid / NCOL;
    const int row = rv % NROW;
    const int view = rv / NROW;

    const float beta = angles[view];
    const float cb = cosf(beta), sb = sinf(beta);
    sp.cb = cb; sp.sb = sb;
    const float u = (col - NCOL * 0.5f + 0.5f) * DET_U;
    const float v = (row - NROW * 0.5f + 0.5f) * DET_V;

    const float sx = ISO * cb, sy = ISO * sb;               // source (z=0)
    const float detx = -(SDD - ISO) * cb - u * sb;
    const float dety = -(SDD - ISO) * sb + u * cb;
    const float detz = v;

    float dx = detx - sx, dy = dety - sy, dz = detz;
    const float inv = 1.0f / sqrtf(dx * dx + dy * dy + dz * dz);
    dx *= inv; dy *= inv; dz *= inv;
    sp.dx = dx; sp.dy = dy; sp.dz = dz;
    sp.bx = sx + 127.5f; sp.by = sy + 127.5f; sp.bz = 127.5f;

    float xl, xh, yl, yh, zl, zh;
    axis_interval(sp.bx, dx, 0.01f, 254.99f, xl, xh);
    axis_interval(sp.by, dy, 0.01f, 254.99f, yl, yh);
    axis_interval(sp.bz, dz, 0.01f, 254.99f, zl, zh);
    const float tin  = fmaxf(xl, fmaxf(yl, zl));
    const float tout = fminf(xh, fminf(yh, zh));

    axis_interval(sp.bx, dx, -1.05f, 256.05f, xl, xh);
    axis_interval(sp.by, dy, -1.05f, 256.05f, yl, yh);
    axis_interval(sp.bz, dz, -1.05f, 256.05f, zl, zh);
    const float glo = fmaxf(xl, fmaxf(yl, zl));
    const float ghi = fminf(xh, fminf(yh, zh));

    const float invdt = 1.0f / DT;
    float g0f = floorf((glo - T0) * invdt - 0.5f);
    float g1f = ceilf((ghi - T0) * invdt - 0.5f) + 1.0f;
    float s0f = ceilf((tin - T0) * invdt - 0.5f + 0.01f);
    float s1f = floorf((tout - T0) * invdt - 0.5f - 0.01f) + 1.0f;
    int g0 = (int)fminf(fmaxf(g0f, 0.0f), 256.0f);
    int g1 = (int)fminf(fmaxf(g1f, 0.0f), 256.0f);
    int s0 = (int)fminf(fmaxf(s0f, 0.0f), 256.0f);
    int s1 = (int)fminf(fmaxf(s1f, 0.0f), 256.0f);
    s0 = max(s0, g0); s1 = min(s1, g1);
    if (s1 < s0) { s0 = g0; s1 = g0; }
    sp.g0 = g0; sp.s0 = s0; sp.s1 = s1; sp.g1 = g1;
    return sp;
}

// ---------- transpose: volT[z][x][y] = vol[z][y][x] --------------------------
__global__ __launch_bounds__(256) void transpose_kernel(const float* __restrict__ vol,
                                                        float* __restrict__ volT) {
    __shared__ float tile[32][33];
    const int z = blockIdx.z;
    const int x0 = blockIdx.x * 32, y0 = blockIdx.y * 32;
    const int tx = threadIdx.x, ty = threadIdx.y;   // 32 x 8
    const float* src = vol + (z << 16);
    float* dst = volT + (z << 16);
    #pragma unroll
    for (int i = 0; i < 32; i += 8)
        tile[ty + i][tx] = src[((y0 + ty + i) << 8) | (x0 + tx)];
    __syncthreads();
    #pragma unroll
    for (int i = 0; i < 32; i += 8)
        dst[((x0 + ty + i) << 8) | (y0 + tx)] = tile[tx][ty + i];
}

// ---------- main: layout-adaptive gathers + 2-deep prefetch pipeline ---------
__global__ __launch_bounds__(256) void projector3d_dual_kernel(
    const float* __restrict__ vol,      // x-inner (original)
    const float* __restrict__ volT,     // y-inner (transposed)
    const float* __restrict__ angles,
    float* __restrict__ out)
{
    // NO swizzle: default dispatch round-robins blocks across XCDs ->
    // all 16 views interleaved -> load balance (bad/good views mixed per XCD).
    const int tid = blockIdx.x * 256 + threadIdx.x;

    const Spans sp = ray_setup(angles, tid);
    const float dx = sp.dx, dy = sp.dy, dz = sp.dz;
    const float bx = sp.bx, by = sp.by, bz = sp.bz;

    // Detector-u axis in volume space is (-sb, cb, 0). Lanes (adjacent cols)
    // spread along it. Pick the layout whose INNER axis matches:
    //   |cb| > |sb| -> lanes spread in y -> use volT (y inner), swap x/y.
    const bool useT = fabsf(sp.cb) > fabsf(sp.sb);
    const float* __restrict__ P = useT ? volT : vol;
    // inner coord a, mid coord b: idx = (z<<16)|(b0<<8)|a0 ; +1 = a, +256 = b
    const float da = useT ? dy : dx, db = useT ? dx : dy;
    const float ba = useT ? by : bx, bb = useT ? bx : by;

    float acc = 0.0f;

    for (int s = sp.g0; s < sp.s0; ++s) {
        const float t = T0 + (s + 0.5f) * DT;
        acc += sample_shell(vol, fmaf(t, dx, bx), fmaf(t, dy, by), fmaf(t, dz, bz));
    }

    int s = sp.s0;
    if (s < sp.s1) {
        // preload sample s
        float t = T0 + (s + 0.5f) * DT;
        float va = fmaf(t, da, ba), vb = fmaf(t, db, bb), vc = fmaf(t, dz, bz);
        float fa0 = floorf(va), fb0 = floorf(vb), fc0 = floorf(vc);
        float fa = va - fa0, fb = vb - fb0, fc = vc - fc0;
        const float* p = P + (((int)fc0 << 16) | ((int)fb0 << 8) | (int)fa0);
        float v000 = p[0],     v001 = p[1];
        float v010 = p[256],   v011 = p[257];
        float v100 = p[65536], v101 = p[65537];
        float v110 = p[65792], v111 = p[65793];

        for (++s; s < sp.s1; ++s) {
            // issue next sample's loads first
            t = T0 + (s + 0.5f) * DT;
            const float nva = fmaf(t, da, ba), nvb = fmaf(t, db, bb), nvc = fmaf(t, dz, bz);
            const float nfa0 = floorf(nva), nfb0 = floorf(nvb), nfc0 = floorf(nvc);
            const float* np = P + (((int)nfc0 << 16) | ((int)nfb0 << 8) | (int)nfa0);
            const float n000 = np[0],     n001 = np[1];
            const float n010 = np[256],   n011 = np[257];
            const float n100 = np[65536], n101 = np[65537];
            const float n110 = np[65792], n111 = np[65793];

            // consume current
            const float c00 = fmaf(fa, v001 - v000, v000);
            const float c01 = fmaf(fa, v011 - v010, v010);
            const float c10 = fmaf(fa, v101 - v100, v100);
            const float c11 = fmaf(fa, v111 - v110, v110);
            const float c0 = fmaf(fb, c01 - c00, c00);
            const float c1 = fmaf(fb, c11 - c10, c10);
            acc += fmaf(fc, c1 - c0, c0);

            // rotate
            fa = nva - nfa0; fb = nvb - nfb0; fc = nvc - nfc0;
            v000 = n000; v001 = n001; v010 = n010; v011 = n011;
            v100 = n100; v101 = n101; v110 = n110; v111 = n111;
        }
        const float c00 = fmaf(fa, v001 - v000, v000);
        const float c01 = fmaf(fa, v011 - v010, v010);
        const float c10 = fmaf(fa, v101 - v100, v100);
        const float c11 = fmaf(fa, v111 - v110, v110);
        const float c0 = fmaf(fb, c01 - c00, c00);
        const float c1 = fmaf(fb, c11 - c10, c10);
        acc += fmaf(fc, c1 - c0, c0);
    }

    for (int s2 = sp.s1; s2 < sp.g1; ++s2) {
        const float t = T0 + (s2 + 0.5f) * DT;
        acc += sample_shell(vol, fmaf(t, dx, bx), fmaf(t, dy, by), fmaf(t, dz, bz));
    }

    out[tid] = acc * DT;
}

// ---------- fallback (single-layout, round-5 style) --------------------------
__global__ __launch_bounds__(256) void projector3d_f32_kernel(
    const float* __restrict__ vol,
    const float* __restrict__ angles,
    float* __restrict__ out)
{
    const int tid = blockIdx.x * 256 + threadIdx.x;
    const Spans sp = ray_setup(angles, tid);
    const float dx = sp.dx, dy = sp.dy, dz = sp.dz;
    const float bx = sp.bx, by = sp.by, bz = sp.bz;

    float acc = 0.0f;
    for (int s = sp.g0; s < sp.s0; ++s) {
        const float t = T0 + (s + 0.5f) * DT;
        acc += sample_shell(vol, fmaf(t, dx, bx), fmaf(t, dy, by), fmaf(t, dz, bz));
    }
    #pragma unroll 4
    for (int s = sp.s0; s < sp.s1; ++s) {
        const float t = T0 + (s + 0.5f) * DT;
        const float vx = fmaf(t, dx, bx), vy = fmaf(t, dy, by), vz = fmaf(t, dz, bz);
        const float fx0 = floorf(vx), fy0 = floorf(vy), fz0 = floorf(vz);
        const int x0 = (int)fx0, y0 = (int)fy0, z0 = (int)fz0;
        const float fx = vx - fx0, fy = vy - fy0, fz = vz - fz0;
        const float* p = vol + ((z0 << 16) | (y0 << 8) | x0);
        const float v000 = p[0],     v001 = p[1];
        const float v010 = p[256],   v011 = p[257];
        const float v100 = p[65536], v101 = p[65537];
        const float v110 = p[65792], v111 = p[65793];
        const float c00 = fmaf(fx, v001 - v000, v000);
        const float c01 = fmaf(fx, v011 - v010, v010);
        const float c10 = fmaf(fx, v101 - v100, v100);
        const float c11 = fmaf(fx, v111 - v110, v110);
        const float c0 = fmaf(fy, c01 - c00, c00);
        const float c1 = fmaf(fy, c11 - c10, c10);
        acc += fmaf(fz, c1 - c0, c0);
    }
    for (int s = sp.s1; s < sp.g1; ++s) {
        const float t = T0 + (s + 0.5f) * DT;
        acc += sample_shell(vol, fmaf(t, dx, bx), fmaf(t, dy, by), fmaf(t, dz, bz));
    }
    out[tid] = acc * DT;
}

extern "C" void kernel_launch(void* const* d_in, const int* in_sizes, int n_in,
                              void* d_out, int out_size, void* d_ws, size_t ws_size,
                              hipStream_t stream) {
    const float* vol    = (const float*)d_in[0];
    const float* angles = (const float*)d_in[1];
    float* out = (float*)d_out;

    const int grid = (NVIEW * NROW * NCOL) / 256;       // 1536
    if (ws_size >= VOL_N * sizeof(float)) {             // 67.1 MB
        float* volT = (float*)d_ws;
        dim3 tgrid(8, 8, 256), tblk(32, 8);
        transpose_kernel<<<tgrid, tblk, 0, stream>>>(vol, volT);
        projector3d_dual_kernel<<<grid, 256, 0, stream>>>(vol, volT, angles, out);
    } else {
        projector3d_f32_kernel<<<grid, 256, 0, stream>>>(vol, angles, out);
    }
}